// Round 13
// baseline (188.174 us; speedup 1.0000x reference)
//
#include <hip/hip_runtime.h>
#include <hip/hip_fp16.h>
#include <cstddef>

#define DIM 2048
#define NTOK 8192
#define NEUMANN_ITERS 6

// Math (validated rounds 1-12):
//   omega = P Q^T, P=[U|V], Q=[sV|-sU], G = Q^T P  (16x16)
//   Y = (I - G/2)^{-1}(I + G/2)  via Neumann-Horner: Y <- B + 0.5*G*Y, B=I+G/2
//   out = x + sum_k c[k] P[:,k],
//   c[k] = 0.5*s* sum_j Z[k][j] b[j],  Z = I + Y,
//     b[j<8] = av[j], b[j>=8] = -au[j-8];  au = x.U, av = x.V
//
// Structural lessons baked in:
//  - No 1-block dispatches (rounds 2/4: ~100 us stall floor).
//  - No per-block redundant gram loop (round 5: ~380 us).
//  - No min-waves clause in launch_bounds (round 6: VGPR cap -> spill).
//  - UV staged once per block in LDS as f16 pairs (rounds 9-12).
//  - Round 12: 32B-lane-stride LDS reads -> 2.16M bank conflicts. THIS
//    round: even/odd pair arrays uvE/uvO, both indexed by quad m -> all
//    ds_read_b128 at 16B lane stride (conflict-free, round-11 pattern).
//  - x loaded ONCE, kept as f16 pairs in regs (32 VGPR); phase 2 has zero
//    global reads. out = f32(f16(x)) + corr adds <=2e-3 abs (thr 0.108).
//  - Full unroll on xh-indexed loops (partial unroll -> runtime reg index
//    -> scratch, rule #20).

typedef _Float16 h2 __attribute__((ext_vector_type(2)));

__device__ __forceinline__ unsigned pkh(float lo, float hi) {
  auto p = __builtin_amdgcn_cvt_pkrtz(lo, hi);   // v_cvt_pkrtz_f16_f32
  return __builtin_bit_cast(unsigned, p);
}
__device__ __forceinline__ h2 cvt2h(float lo, float hi) {
  auto p = __builtin_amdgcn_cvt_pkrtz(lo, hi);
  return __builtin_bit_cast(h2, p);
}

template <int CTRL>
__device__ __forceinline__ float dpp_add(float v) {
  const int t =
      __builtin_amdgcn_update_dpp(0, __float_as_int(v), CTRL, 0xf, 0xf, true);
  return v + __int_as_float(t);
}
__device__ __forceinline__ float wave_red(float v) {
  v = dpp_add<0xB1>(v);    // quad_perm [1,0,3,2]  (xor 1)
  v = dpp_add<0x4E>(v);    // quad_perm [2,3,0,1]  (xor 2)
  v = dpp_add<0x141>(v);   // row_half_mirror      (pairs halves of 8)
  v = dpp_add<0x140>(v);   // row_mirror           (pairs halves of 16)
  v += __shfl_xor(v, 16, 64);
  v += __shfl_xor(v, 32, 64);
  return v;
}

// ---------------------------------------------------------------------------
// 1) Gram: one block per entry e=(q,i,j); 256 threads reduce over d=2048.
// ---------------------------------------------------------------------------
__global__ __launch_bounds__(256) void rora_gram(
    const float* __restrict__ U, const float* __restrict__ V,
    float* __restrict__ prod) {
  const int e = blockIdx.x;            // 0..191
  const int q = e >> 6;                // 0: U^T U, 1: U^T V, 2: V^T V
  const int i = (e >> 3) & 7, j = e & 7;
  const float* A = (q == 2) ? V : U;
  const float* B = (q == 0) ? U : V;
  const int t = threadIdx.x;
  float acc = 0.f;
#pragma unroll
  for (int s = 0; s < 8; ++s) {
    const int d = s * 256 + t;
    acc = fmaf(A[d * 8 + i], B[d * 8 + j], acc);
  }
#pragma unroll
  for (int m = 1; m < 64; m <<= 1) acc += __shfl_xor(acc, m, 64);
  __shared__ float wsum[4];
  if ((t & 63) == 0) wsum[t >> 6] = acc;
  __syncthreads();
  if (t == 0) prod[e] = (wsum[0] + wsum[1]) + (wsum[2] + wsum[3]);
}

// ---------------------------------------------------------------------------
// 2) Fused. LDS layout (quad m covers d = 4m..4m+3):
//    uvE[q][m].comp(c) = half2( W[4m  ][4q+c], W[4m+1][4q+c] )
//    uvO[q][m].comp(c) = half2( W[4m+2][4q+c], W[4m+3][4q+c] )
//    q=0: U cols 0-3 (slots 0-3), q=1: U 4-7, q=2: V 0-3 (slots 8-11),
//    q=3: V 4-7 (slots 12-15).
// ---------------------------------------------------------------------------
__global__ __launch_bounds__(512) void rora_fused(
    const float* __restrict__ x, const float* __restrict__ U,
    const float* __restrict__ V, const float* __restrict__ gate,
    const float* __restrict__ prod, float* __restrict__ out) {
  __shared__ uint4 uvE[4][DIM / 4];   // 32 KB
  __shared__ uint4 uvO[4][DIM / 4];   // 32 KB
  __shared__ float prodS[192];        // [q*64 + i*8 + j]
  __shared__ float Gs[16][17];
  __shared__ float Bm[16][17];
  __shared__ float Ya[16][17];
  __shared__ float Yb[16][17];
  const int t = threadIdx.x;

  // ---- stage U,V -> LDS; thread t owns quad Q=t (d = 4t..4t+3) ----
  {
    const float4* U4 = (const float4*)U;
    const float4* V4 = (const float4*)V;
    const int Q = t;
    const float4 u0 = U4[8 * Q + 0], u1 = U4[8 * Q + 1];
    const float4 u2 = U4[8 * Q + 2], u3 = U4[8 * Q + 3];
    const float4 u4 = U4[8 * Q + 4], u5 = U4[8 * Q + 5];
    const float4 u6 = U4[8 * Q + 6], u7 = U4[8 * Q + 7];
    const float4 v0 = V4[8 * Q + 0], v1 = V4[8 * Q + 1];
    const float4 v2 = V4[8 * Q + 2], v3 = V4[8 * Q + 3];
    const float4 v4 = V4[8 * Q + 4], v5 = V4[8 * Q + 5];
    const float4 v6 = V4[8 * Q + 6], v7 = V4[8 * Q + 7];
    uvE[0][Q] = make_uint4(pkh(u0.x, u2.x), pkh(u0.y, u2.y),
                           pkh(u0.z, u2.z), pkh(u0.w, u2.w));
    uvE[1][Q] = make_uint4(pkh(u1.x, u3.x), pkh(u1.y, u3.y),
                           pkh(u1.z, u3.z), pkh(u1.w, u3.w));
    uvO[0][Q] = make_uint4(pkh(u4.x, u6.x), pkh(u4.y, u6.y),
                           pkh(u4.z, u6.z), pkh(u4.w, u6.w));
    uvO[1][Q] = make_uint4(pkh(u5.x, u7.x), pkh(u5.y, u7.y),
                           pkh(u5.z, u7.z), pkh(u5.w, u7.w));
    uvE[2][Q] = make_uint4(pkh(v0.x, v2.x), pkh(v0.y, v2.y),
                           pkh(v0.z, v2.z), pkh(v0.w, v2.w));
    uvE[3][Q] = make_uint4(pkh(v1.x, v3.x), pkh(v1.y, v3.y),
                           pkh(v1.z, v3.z), pkh(v1.w, v3.w));
    uvO[2][Q] = make_uint4(pkh(v4.x, v6.x), pkh(v4.y, v6.y),
                           pkh(v4.z, v6.z), pkh(v4.w, v6.w));
    uvO[3][Q] = make_uint4(pkh(v5.x, v7.x), pkh(v5.y, v7.y),
                           pkh(v5.z, v7.z), pkh(v5.w, v7.w));
  }

  // ---- 16x16 setup (f32, from ws gram products) ----
  if (t < 192) prodS[t] = prod[t];
  __syncthreads();
  const float sg = 1.f / (1.f + expf(-gate[0]));
  if (t < 256) {
    const int r = t >> 4, c = t & 15;
    float g;
    if (r < 8) g = (c < 8) ? sg * prodS[64 + c * 8 + r]              // (V^T U)
                           : sg * prodS[128 + r * 8 + (c - 8)];      // (V^T V)
    else       g = (c < 8) ? -sg * prodS[(r - 8) * 8 + c]            // -(U^T U)
                           : -sg * prodS[64 + (r - 8) * 8 + (c - 8)];
    const float b = ((r == c) ? 1.f : 0.f) + 0.5f * g;
    Gs[r][c] = g;
    Bm[r][c] = b;
    Ya[r][c] = b;
  }
  __syncthreads();
#pragma unroll
  for (int m = 0; m < NEUMANN_ITERS; ++m) {   // ends in Ya (last m odd)
    if (t < 256) {
      const int r = t >> 4, c = t & 15;
      const float (*Yp)[17] = (m & 1) ? Yb : Ya;
      float (*Yn)[17] = (m & 1) ? Ya : Yb;
      float acc = Bm[r][c];
#pragma unroll
      for (int j = 0; j < 16; ++j)
        acc = fmaf(0.5f * Gs[r][j], Yp[j][c], acc);
      Yn[r][c] = acc;
    }
    __syncthreads();   // final barrier also orders uvE/uvO staging
  }

  // ---- main: 8 waves, 2 rows/wave; lane owns quads m = i*64+lane ----
  const int wv = t >> 6, lane = t & 63;
  const int row0 = blockIdx.x * 16 + wv * 2;
  const float4* x4A = (const float4*)(x + (size_t)row0 * DIM);
  const float4* x4B = x4A + DIM / 4;

  // x loaded ONCE, kept as f16 pairs (32 VGPR); phase 2 reads no globals.
  h2 xA0[8], xA1[8], xB0[8], xB1[8];
#pragma unroll
  for (int i = 0; i < 8; ++i) {
    const float4 a = x4A[i * 64 + lane];
    const float4 b = x4B[i * 64 + lane];
    xA0[i] = cvt2h(a.x, a.y);  xA1[i] = cvt2h(a.z, a.w);
    xB0[i] = cvt2h(b.x, b.y);  xB1[i] = cvt2h(b.z, b.w);
  }

  float a0[16], a1[16];
#pragma unroll
  for (int k = 0; k < 16; ++k) { a0[k] = 0.f; a1[k] = 0.f; }

#if __has_builtin(__builtin_amdgcn_fdot2)
#define D2(acc, xp, w) \
  acc = __builtin_amdgcn_fdot2(xp, __builtin_bit_cast(h2, w), acc, false)
#else
#define D2(acc, xp, w)                                                  \
  {                                                                     \
    const __half2 _u = __builtin_bit_cast(__half2, w);                  \
    acc = fmaf((float)(xp)[0], __low2float(_u),                         \
               fmaf((float)(xp)[1], __high2float(_u), acc));            \
  }
#endif
#define KQ(arr, base, W, xp)      \
  D2(arr[base + 0], xp, W.x);     \
  D2(arr[base + 1], xp, W.y);     \
  D2(arr[base + 2], xp, W.z);     \
  D2(arr[base + 3], xp, W.w);

  // phase 1: a = [x.U | x.V]   (all LDS reads at 16B lane stride)
#pragma unroll
  for (int i = 0; i < 8; ++i) {
    const int m = i * 64 + lane;
    const uint4 E0 = uvE[0][m], E1 = uvE[1][m];
    const uint4 E2 = uvE[2][m], E3 = uvE[3][m];
    const uint4 O0 = uvO[0][m], O1 = uvO[1][m];
    const uint4 O2 = uvO[2][m], O3 = uvO[3][m];
    KQ(a0, 0, E0, xA0[i]);  KQ(a0, 4, E1, xA0[i]);
    KQ(a0, 8, E2, xA0[i]);  KQ(a0, 12, E3, xA0[i]);
    KQ(a0, 0, O0, xA1[i]);  KQ(a0, 4, O1, xA1[i]);
    KQ(a0, 8, O2, xA1[i]);  KQ(a0, 12, O3, xA1[i]);
    KQ(a1, 0, E0, xB0[i]);  KQ(a1, 4, E1, xB0[i]);
    KQ(a1, 8, E2, xB0[i]);  KQ(a1, 12, E3, xB0[i]);
    KQ(a1, 0, O0, xB1[i]);  KQ(a1, 4, O1, xB1[i]);
    KQ(a1, 8, O2, xB1[i]);  KQ(a1, 12, O3, xB1[i]);
  }
#undef KQ
#undef D2

  // butterfly: 4 DPP VALU levels + 2 shuffles per value
#pragma unroll
  for (int k = 0; k < 16; ++k) {
    a0[k] = wave_red(a0[k]);
    a1[k] = wave_red(a1[k]);
  }

  // c[k] = 0.5*s * sum_j Z[k][j] b[j]; lane kk=lane&15 computes row kk.
  __half2 ch0[16], ch1[16];
  {
    const int kk = lane & 15;
    float zrow[16];
#pragma unroll
    for (int j = 0; j < 16; ++j)
      zrow[j] = Ya[kk][j] + ((j == kk) ? 1.f : 0.f);
    const float hs = 0.5f * sg;
    float s0 = 0.f, s1 = 0.f;
#pragma unroll
    for (int j = 0; j < 8; ++j) {
      s0 = fmaf(zrow[j], a0[8 + j], s0);     //  Z[k][j]   * av[j]
      s0 = fmaf(-zrow[8 + j], a0[j], s0);    // -Z[k][8+j] * au[j]
      s1 = fmaf(zrow[j], a1[8 + j], s1);
      s1 = fmaf(-zrow[8 + j], a1[j], s1);
    }
    const float cp0 = hs * s0, cp1 = hs * s1;
#pragma unroll
    for (int k = 0; k < 16; ++k) {
      ch0[k] = __float2half2_rn(__shfl(cp0, k, 64));
      ch1[k] = __float2half2_rn(__shfl(cp1, k, 64));
    }
  }

  // phase 2: out = f32(x_h16) + corr; no global reads, depth-8 hfma2 chains
  float4* o4A = (float4*)(out + (size_t)row0 * DIM);
  float4* o4B = o4A + DIM / 4;
  const __half2 hz = __float2half2_rn(0.f);
#define HF2(acc, c, w) acc = __hfma2(c, __builtin_bit_cast(__half2, w), acc)
#pragma unroll
  for (int i = 0; i < 8; ++i) {
    const int m = i * 64 + lane;
    const uint4 E0 = uvE[0][m], E1 = uvE[1][m];
    const uint4 E2 = uvE[2][m], E3 = uvE[3][m];
    const uint4 O0 = uvO[0][m], O1 = uvO[1][m];
    const uint4 O2 = uvO[2][m], O3 = uvO[3][m];
    // row A: even pair (d=4m,4m+1) and odd pair (d=4m+2,4m+3)
    __half2 eA0 = hz, eA1 = hz, oA0 = hz, oA1 = hz;
    HF2(eA0, ch0[0], E0.x);  HF2(eA0, ch0[1], E0.y);
    HF2(eA0, ch0[2], E0.z);  HF2(eA0, ch0[3], E0.w);
    HF2(eA0, ch0[4], E1.x);  HF2(eA0, ch0[5], E1.y);
    HF2(eA0, ch0[6], E1.z);  HF2(eA0, ch0[7], E1.w);
    HF2(eA1, ch0[8], E2.x);  HF2(eA1, ch0[9], E2.y);
    HF2(eA1, ch0[10], E2.z); HF2(eA1, ch0[11], E2.w);
    HF2(eA1, ch0[12], E3.x); HF2(eA1, ch0[13], E3.y);
    HF2(eA1, ch0[14], E3.z); HF2(eA1, ch0[15], E3.w);
    HF2(oA0, ch0[0], O0.x);  HF2(oA0, ch0[1], O0.y);
    HF2(oA0, ch0[2], O0.z);  HF2(oA0, ch0[3], O0.w);
    HF2(oA0, ch0[4], O1.x);  HF2(oA0, ch0[5], O1.y);
    HF2(oA0, ch0[6], O1.z);  HF2(oA0, ch0[7], O1.w);
    HF2(oA1, ch0[8], O2.x);  HF2(oA1, ch0[9], O2.y);
    HF2(oA1, ch0[10], O2.z); HF2(oA1, ch0[11], O2.w);
    HF2(oA1, ch0[12], O3.x); HF2(oA1, ch0[13], O3.y);
    HF2(oA1, ch0[14], O3.z); HF2(oA1, ch0[15], O3.w);
    const __half2 sEA = __hadd2(eA0, eA1);
    const __half2 sOA = __hadd2(oA0, oA1);
    float4 oA;
    oA.x = (float)(xA0[i])[0] + __low2float(sEA);
    oA.y = (float)(xA0[i])[1] + __high2float(sEA);
    oA.z = (float)(xA1[i])[0] + __low2float(sOA);
    oA.w = (float)(xA1[i])[1] + __high2float(sOA);
    o4A[m] = oA;
    // row B
    __half2 eB0 = hz, eB1 = hz, oB0 = hz, oB1 = hz;
    HF2(eB0, ch1[0], E0.x);  HF2(eB0, ch1[1], E0.y);
    HF2(eB0, ch1[2], E0.z);  HF2(eB0, ch1[3], E0.w);
    HF2(eB0, ch1[4], E1.x);  HF2(eB0, ch1[5], E1.y);
    HF2(eB0, ch1[6], E1.z);  HF2(eB0, ch1[7], E1.w);
    HF2(eB1, ch1[8], E2.x);  HF2(eB1, ch1[9], E2.y);
    HF2(eB1, ch1[10], E2.z); HF2(eB1, ch1[11], E2.w);
    HF2(eB1, ch1[12], E3.x); HF2(eB1, ch1[13], E3.y);
    HF2(eB1, ch1[14], E3.z); HF2(eB1, ch1[15], E3.w);
    HF2(oB0, ch1[0], O0.x);  HF2(oB0, ch1[1], O0.y);
    HF2(oB0, ch1[2], O0.z);  HF2(oB0, ch1[3], O0.w);
    HF2(oB0, ch1[4], O1.x);  HF2(oB0, ch1[5], O1.y);
    HF2(oB0, ch1[6], O1.z);  HF2(oB0, ch1[7], O1.w);
    HF2(oB1, ch1[8], O2.x);  HF2(oB1, ch1[9], O2.y);
    HF2(oB1, ch1[10], O2.z); HF2(oB1, ch1[11], O2.w);
    HF2(oB1, ch1[12], O3.x); HF2(oB1, ch1[13], O3.y);
    HF2(oB1, ch1[14], O3.z); HF2(oB1, ch1[15], O3.w);
    const __half2 sEB = __hadd2(eB0, eB1);
    const __half2 sOB = __hadd2(oB0, oB1);
    float4 oB;
    oB.x = (float)(xB0[i])[0] + __low2float(sEB);
    oB.y = (float)(xB0[i])[1] + __high2float(sEB);
    oB.z = (float)(xB1[i])[0] + __low2float(sOB);
    oB.w = (float)(xB1[i])[1] + __high2float(sOB);
    o4B[m] = oB;
  }
#undef HF2
}

extern "C" void kernel_launch(void* const* d_in, const int* in_sizes, int n_in,
                              void* d_out, int out_size, void* d_ws, size_t ws_size,
                              hipStream_t stream) {
  const float* x    = (const float*)d_in[0];
  const float* U    = (const float*)d_in[1];
  const float* V    = (const float*)d_in[2];
  const float* gate = (const float*)d_in[3];
  float* out = (float*)d_out;
  float* prodw = (float*)d_ws;   // 192 floats

  rora_gram<<<192, 256, 0, stream>>>(U, V, prodw);
  rora_fused<<<NTOK / 16, 512, 0, stream>>>(x, U, V, gate, prodw, out);
}

// Round 15
// 54.479 us; speedup vs baseline: 3.4541x; 3.4541x over previous
//
#include <hip/hip_runtime.h>
#include <cstddef>

#define DIM 2048
#define NTOK 8192
#define NEUMANN_ITERS 6
#define S8 64.0f          // fp8 pre-scale: U,V ~ 0.01*N(0,1) -> ~0.64 (normal range)

// Math (validated rounds 1-13):
//   omega = P Q^T, P=[U|V], Q=[sV|-sU], G = Q^T P  (16x16)
//   Y = (I - G/2)^{-1}(I + G/2)  via Neumann-Horner: Y <- B + 0.5*G*Y, B=I+G/2
//   out = x + sum_k c[k] P[:,k],
//   c[k] = 0.5*s* sum_j Z[k][j] b[j],  Z = I + Y,
//     b[j<8] = av[j], b[j>=8] = -au[j-8];  au = x.U, av = x.V
//   With W stored scaled by S8: a_meas = S8*a_true -> hs = 0.5*s/(S8*S8).
//   Gram/Neumann stay f32-exact (from global U/V).
//
// Structural lessons baked in:
//  - No 1-block dispatches (r2/4: ~100us stall floor). No redundant per-block
//    gram (r5). No min-waves launch_bounds clause (r6: spill).
//  - r13: x-in-registers blew VGPR to 128 + spill. Keep VGPR <= 64.
//  - r11/r12: latency-bound at 16 waves/CU (LDS 69KB -> 2 blocks/CU).
//    UV as fp8e4m3 (x64) -> 32KB LDS -> ~38KB total -> 4 blocks/CU
//    x 8 waves = 32 waves/CU (HW max). 1 row/wave, grid 1024.
//  - LDS reads uint4 @16B lane stride (r12: 32B stride = 2.16M conflicts).
//  - r14 compile lesson: cvt_pk_f32_fp8's word-select must be a LITERAL
//    constant -> template parameter, not a function argument.
//  - No runtime indexing of register arrays.

#if __has_builtin(__builtin_amdgcn_cvt_pk_f32_fp8) && \
    __has_builtin(__builtin_amdgcn_cvt_pk_fp8_f32)
#define HW_FP8 1
#else
#define HW_FP8 0
// Software OCP e4m3 (fallback only; self-consistent encode/decode)
__device__ __forceinline__ float dec8_sw(unsigned u) {
  const unsigned e = (u >> 3) & 15u, m = u & 7u;
  const float mag = e ? __uint_as_float(((e + 120u) << 23) | (m << 20))
                      : (float)m * 0.001953125f;   // m * 2^-9
  return (u & 0x80u) ? -mag : mag;
}
__device__ __forceinline__ unsigned enc8_sw(float v) {
  const unsigned sign = (__float_as_uint(v) >> 24) & 0x80u;
  const float av = fminf(fabsf(v), 448.f);
  unsigned code;
  if (av < 0.015625f) {
    code = (unsigned)__float2int_rn(av * 512.f);   // subnormal; carry ok
  } else {
    const unsigned ui = __float_as_uint(av) + (1u << 19);
    const unsigned e = (ui >> 23) - 120u;
    code = (e << 3) | ((ui >> 20) & 7u);
    if (code > 0x7Eu) code = 0x7Eu;
  }
  return code | sign;
}
#endif

// pack pair-words: low half = col c0 (d_even, d_odd), high half = col c1
__device__ __forceinline__ unsigned pk8q(float l0, float l1, float h0, float h1) {
#if HW_FP8
  int w = __builtin_amdgcn_cvt_pk_fp8_f32(l0, l1, 0, false);
  w = __builtin_amdgcn_cvt_pk_fp8_f32(h0, h1, w, true);
  return (unsigned)w;
#else
  return enc8_sw(l0) | (enc8_sw(l1) << 8) | (enc8_sw(h0) << 16) |
         (enc8_sw(h1) << 24);
#endif
}
template <bool HI>
__device__ __forceinline__ float2 unpk8(unsigned w) {
#if HW_FP8
  auto p = __builtin_amdgcn_cvt_pk_f32_fp8((int)w, HI);   // literal word-select
  return make_float2(p[0], p[1]);
#else
  const unsigned pp = HI ? (w >> 16) : w;
  return make_float2(dec8_sw(pp & 0xffu), dec8_sw((pp >> 8) & 0xffu));
#endif
}

template <int CTRL>
__device__ __forceinline__ float dpp_add(float v) {
  const int t =
      __builtin_amdgcn_update_dpp(0, __float_as_int(v), CTRL, 0xf, 0xf, true);
  return v + __int_as_float(t);
}
__device__ __forceinline__ float wave_red(float v) {
  v = dpp_add<0xB1>(v);    // quad_perm [1,0,3,2]  (xor 1)
  v = dpp_add<0x4E>(v);    // quad_perm [2,3,0,1]  (xor 2)
  v = dpp_add<0x141>(v);   // row_half_mirror
  v = dpp_add<0x140>(v);   // row_mirror
  v += __shfl_xor(v, 16, 64);
  v += __shfl_xor(v, 32, 64);
  return v;
}

// ---------------------------------------------------------------------------
// 1) Gram: one block per entry e=(q,i,j); 256 threads reduce over d=2048.
// ---------------------------------------------------------------------------
__global__ __launch_bounds__(256) void rora_gram(
    const float* __restrict__ U, const float* __restrict__ V,
    float* __restrict__ prod) {
  const int e = blockIdx.x;            // 0..191
  const int q = e >> 6;                // 0: U^T U, 1: U^T V, 2: V^T V
  const int i = (e >> 3) & 7, j = e & 7;
  const float* A = (q == 2) ? V : U;
  const float* B = (q == 0) ? U : V;
  const int t = threadIdx.x;
  float acc = 0.f;
#pragma unroll
  for (int s = 0; s < 8; ++s) {
    const int d = s * 256 + t;
    acc = fmaf(A[d * 8 + i], B[d * 8 + j], acc);
  }
#pragma unroll
  for (int m = 1; m < 64; m <<= 1) acc += __shfl_xor(acc, m, 64);
  __shared__ float wsum[4];
  if ((t & 63) == 0) wsum[t >> 6] = acc;
  __syncthreads();
  if (t == 0) prod[e] = (wsum[0] + wsum[1]) + (wsum[2] + wsum[3]);
}

// ---------------------------------------------------------------------------
// 2) Fused. LDS: uvF[0][P] = U cols 0-7, uvF[1][P] = V cols 0-7 for d-pair
//    P (d=2P,2P+1); each uint32 = 2 cols x (d_even,d_odd) fp8, scaled x64.
//    512 thr = 8 waves x 1 row; grid 1024; ~38KB LDS -> 4 blocks/CU.
// ---------------------------------------------------------------------------
__global__ __launch_bounds__(512) void rora_fused(
    const float* __restrict__ x, const float* __restrict__ U,
    const float* __restrict__ V, const float* __restrict__ gate,
    const float* __restrict__ prod, float* __restrict__ out) {
  __shared__ uint4 uvF[2][DIM / 2];   // 32 KB
  __shared__ float prodS[192];        // [q*64 + i*8 + j]
  __shared__ float Gs[16][17];
  __shared__ float Bm[16][17];
  __shared__ float Ya[16][17];
  __shared__ float Yb[16][17];
  const int t = threadIdx.x;

  // ---- stage U,V -> LDS as scaled fp8 ----
  {
    const float4* U4 = (const float4*)U;
    const float4* V4 = (const float4*)V;
#pragma unroll
    for (int rep = 0; rep < 2; ++rep) {
      const int P = rep * 512 + t;     // d-pair (2P, 2P+1)
      const float4 u0 = U4[4 * P + 0], u1 = U4[4 * P + 1];  // U[2P][0..7]
      const float4 u2 = U4[4 * P + 2], u3 = U4[4 * P + 3];  // U[2P+1][0..7]
      const float4 v0 = V4[4 * P + 0], v1 = V4[4 * P + 1];
      const float4 v2 = V4[4 * P + 2], v3 = V4[4 * P + 3];
      uvF[0][P] = make_uint4(
          pk8q(u0.x * S8, u2.x * S8, u0.y * S8, u2.y * S8),
          pk8q(u0.z * S8, u2.z * S8, u0.w * S8, u2.w * S8),
          pk8q(u1.x * S8, u3.x * S8, u1.y * S8, u3.y * S8),
          pk8q(u1.z * S8, u3.z * S8, u1.w * S8, u3.w * S8));
      uvF[1][P] = make_uint4(
          pk8q(v0.x * S8, v2.x * S8, v0.y * S8, v2.y * S8),
          pk8q(v0.z * S8, v2.z * S8, v0.w * S8, v2.w * S8),
          pk8q(v1.x * S8, v3.x * S8, v1.y * S8, v3.y * S8),
          pk8q(v1.z * S8, v3.z * S8, v1.w * S8, v3.w * S8));
    }
  }

  // ---- 16x16 setup (f32, from ws gram products) ----
  if (t < 192) prodS[t] = prod[t];
  __syncthreads();
  const float sg = 1.f / (1.f + expf(-gate[0]));
  if (t < 256) {
    const int r = t >> 4, c = t & 15;
    float g;
    if (r < 8) g = (c < 8) ? sg * prodS[64 + c * 8 + r]              // (V^T U)
                           : sg * prodS[128 + r * 8 + (c - 8)];      // (V^T V)
    else       g = (c < 8) ? -sg * prodS[(r - 8) * 8 + c]            // -(U^T U)
                           : -sg * prodS[64 + (r - 8) * 8 + (c - 8)];
    const float b = ((r == c) ? 1.f : 0.f) + 0.5f * g;
    Gs[r][c] = g;
    Bm[r][c] = b;
    Ya[r][c] = b;
  }
  __syncthreads();
#pragma unroll
  for (int m = 0; m < NEUMANN_ITERS; ++m) {   // ends in Ya (last m odd)
    if (t < 256) {
      const int r = t >> 4, c = t & 15;
      const float (*Yp)[17] = (m & 1) ? Yb : Ya;
      float (*Yn)[17] = (m & 1) ? Ya : Yb;
      float acc = Bm[r][c];
#pragma unroll
      for (int j = 0; j < 16; ++j)
        acc = fmaf(0.5f * Gs[r][j], Yp[j][c], acc);
      Yn[r][c] = acc;
    }
    __syncthreads();   // final barrier also orders uvF staging
  }

  // ---- main: 8 waves, 1 row/wave; lane owns d-pairs P = i*64+lane ----
  const int wv = t >> 6, lane = t & 63;
  const int row = blockIdx.x * 8 + wv;
  const float2* x2 = (const float2*)(x + (size_t)row * DIM);

  float a[16];
#pragma unroll
  for (int k = 0; k < 16; ++k) a[k] = 0.f;

  // phase 1: a = [x.U | x.V] (scaled by S8)
#define W2(w, b)                                              \
  {                                                           \
    const float2 p0 = unpk8<false>(w);                        \
    const float2 p1 = unpk8<true>(w);                         \
    a[b] = fmaf(xp.x, p0.x, fmaf(xp.y, p0.y, a[b]));          \
    a[b + 1] = fmaf(xp.x, p1.x, fmaf(xp.y, p1.y, a[b + 1]));  \
  }
#pragma unroll 4
  for (int i = 0; i < 16; ++i) {
    const int P = i * 64 + lane;
    const float2 xp = x2[P];
    const uint4 WU = uvF[0][P], WV = uvF[1][P];
    W2(WU.x, 0)  W2(WU.y, 2)  W2(WU.z, 4)  W2(WU.w, 6)
    W2(WV.x, 8)  W2(WV.y, 10) W2(WV.z, 12) W2(WV.w, 14)
  }
#undef W2

  // butterfly: 4 DPP VALU levels + 2 shuffles per value
#pragma unroll
  for (int k = 0; k < 16; ++k) a[k] = wave_red(a[k]);

  // c[k] = (0.5*s/S8^2) * sum_j Z[k][j] b[j]; lane kk=lane&15 does row kk.
  {
    const int kk = lane & 15;
    float zrow[16];
#pragma unroll
    for (int j = 0; j < 16; ++j)
      zrow[j] = Ya[kk][j] + ((j == kk) ? 1.f : 0.f);
    const float hs = 0.5f * sg / (S8 * S8);
    float s = 0.f;
#pragma unroll
    for (int j = 0; j < 8; ++j) {
      s = fmaf(zrow[j], a[8 + j], s);     //  Z[k][j]   * av[j]
      s = fmaf(-zrow[8 + j], a[j], s);    // -Z[k][8+j] * au[j]
    }
    const float cp = hs * s;
#pragma unroll
    for (int k = 0; k < 16; ++k) a[k] = __shfl(cp, k, 64);
  }

  // phase 2: out = x + sum_k c[k]*W[d][k] (W scaled; c pre-divided)
  float2* o2 = (float2*)(out + (size_t)row * DIM);
#define C2(w, b)                                              \
  {                                                           \
    const float2 p0 = unpk8<false>(w);                        \
    const float2 p1 = unpk8<true>(w);                         \
    cE = fmaf(a[b], p0.x, fmaf(a[b + 1], p1.x, cE));          \
    cO = fmaf(a[b], p0.y, fmaf(a[b + 1], p1.y, cO));          \
  }
#pragma unroll 4
  for (int i = 0; i < 16; ++i) {
    const int P = i * 64 + lane;
    const float2 xp = x2[P];
    const uint4 WU = uvF[0][P], WV = uvF[1][P];
    float cE = 0.f, cO = 0.f;
    C2(WU.x, 0)  C2(WU.y, 2)  C2(WU.z, 4)  C2(WU.w, 6)
    C2(WV.x, 8)  C2(WV.y, 10) C2(WV.z, 12) C2(WV.w, 14)
    o2[P] = make_float2(xp.x + cE, xp.y + cO);
  }
#undef C2
}

extern "C" void kernel_launch(void* const* d_in, const int* in_sizes, int n_in,
                              void* d_out, int out_size, void* d_ws, size_t ws_size,
                              hipStream_t stream) {
  const float* x    = (const float*)d_in[0];
  const float* U    = (const float*)d_in[1];
  const float* V    = (const float*)d_in[2];
  const float* gate = (const float*)d_in[3];
  float* out = (float*)d_out;
  float* prodw = (float*)d_ws;   // 192 floats

  rora_gram<<<192, 256, 0, stream>>>(U, V, prodw);
  rora_fused<<<NTOK / 8, 512, 0, stream>>>(x, U, V, gate, prodw, out);
}

// Round 16
// 45.106 us; speedup vs baseline: 4.1718x; 1.2078x over previous
//
#include <hip/hip_runtime.h>
#include <hip/hip_fp16.h>
#include <cstddef>

#define DIM 2048
#define NTOK 8192
#define NEUMANN_ITERS 6

// Math (validated rounds 1-15):
//   omega = P Q^T, P=[U|V], Q=[sV|-sU], G = Q^T P  (16x16)
//   Y = (I - G/2)^{-1}(I + G/2)  via Neumann-Horner: Y <- B + 0.5*G*Y, B=I+G/2
//   out = x + sum_k c[k] P[:,k],
//   c[k] = 0.5*s* sum_j Z[k][j] b[j],  Z = I + Y,
//     b[j<8] = av[j], b[j>=8] = -au[j-8];  au = x.U, av = x.V
//
// Structural lessons baked in:
//  - No 1-block dispatches (r2/4: ~100us stall floor). No redundant per-block
//    gram (r5). No min-waves launch_bounds clause (r6: spill).
//  - UV staged once per block in LDS as f16 pairs + fdot2 (r11 champion path;
//    r15 fp8 regressed: decode = 1 MAC/inst vs fdot2's 2, VALU 26->45%).
//  - r13: x-in-regs spilled; x re-read from global in phase 2 (L2/L3-hot).
//  - r12: LDS reads must stay at 16B lane stride (32B = 2.16M conflicts).
//  - r15 lesson: more blocks/CU didn't raise occupancy. THIS round: more
//    waves/BLOCK - 1024 thr = 16 waves, 1 row/wave, same 69KB LDS ->
//    2 blocks/CU x 16 waves = 32 waves/CU (HW max), 2x round 11's TLP.
//  - cvt_pkrtz returns __fp16 ext_vector(2): bit_cast everywhere.
//  - No runtime indexing of register arrays.

typedef _Float16 h2 __attribute__((ext_vector_type(2)));

__device__ __forceinline__ unsigned pkh(float lo, float hi) {
  auto p = __builtin_amdgcn_cvt_pkrtz(lo, hi);   // v_cvt_pkrtz_f16_f32
  return __builtin_bit_cast(unsigned, p);
}
__device__ __forceinline__ h2 cvt2h(float lo, float hi) {
  auto p = __builtin_amdgcn_cvt_pkrtz(lo, hi);
  return __builtin_bit_cast(h2, p);
}

template <int CTRL>
__device__ __forceinline__ float dpp_add(float v) {
  const int t =
      __builtin_amdgcn_update_dpp(0, __float_as_int(v), CTRL, 0xf, 0xf, true);
  return v + __int_as_float(t);
}
__device__ __forceinline__ float wave_red(float v) {
  v = dpp_add<0xB1>(v);    // quad_perm [1,0,3,2]  (xor 1)
  v = dpp_add<0x4E>(v);    // quad_perm [2,3,0,1]  (xor 2)
  v = dpp_add<0x141>(v);   // row_half_mirror      (pairs halves of 8)
  v = dpp_add<0x140>(v);   // row_mirror           (pairs halves of 16)
  v += __shfl_xor(v, 16, 64);
  v += __shfl_xor(v, 32, 64);
  return v;
}

// ---------------------------------------------------------------------------
// 1) Gram: one block per entry e=(q,i,j); 256 threads reduce over d=2048.
// ---------------------------------------------------------------------------
__global__ __launch_bounds__(256) void rora_gram(
    const float* __restrict__ U, const float* __restrict__ V,
    float* __restrict__ prod) {
  const int e = blockIdx.x;            // 0..191
  const int q = e >> 6;                // 0: U^T U, 1: U^T V, 2: V^T V
  const int i = (e >> 3) & 7, j = e & 7;
  const float* A = (q == 2) ? V : U;
  const float* B = (q == 0) ? U : V;
  const int t = threadIdx.x;
  float acc = 0.f;
#pragma unroll
  for (int s = 0; s < 8; ++s) {
    const int d = s * 256 + t;
    acc = fmaf(A[d * 8 + i], B[d * 8 + j], acc);
  }
#pragma unroll
  for (int m = 1; m < 64; m <<= 1) acc += __shfl_xor(acc, m, 64);
  __shared__ float wsum[4];
  if ((t & 63) == 0) wsum[t >> 6] = acc;
  __syncthreads();
  if (t == 0) prod[e] = (wsum[0] + wsum[1]) + (wsum[2] + wsum[3]);
}

// ---------------------------------------------------------------------------
// 2) Fused: UV->LDS f16-pair staging + 16x16 setup + streaming main.
//    1024 threads = 16 waves x 1 row; grid 512; 2 blocks/CU = 32 waves/CU.
//    uvQ[q][P].comp(m) = half2( W[2P][4q+m], W[2P+1][4q+m] ),
//      slots: q=0 U cols 0-3, q=1 U cols 4-7, q=2 V cols 0-3, q=3 V cols 4-7.
// ---------------------------------------------------------------------------
__global__ __launch_bounds__(1024) void rora_fused(
    const float* __restrict__ x, const float* __restrict__ U,
    const float* __restrict__ V, const float* __restrict__ gate,
    const float* __restrict__ prod, float* __restrict__ out) {
  __shared__ uint4 uvQ[4][DIM / 2];   // 64 KB
  __shared__ float prodS[192];        // [q*64 + i*8 + j]
  __shared__ float Gs[16][17];
  __shared__ float Bm[16][17];
  __shared__ float Ya[16][17];
  __shared__ float Yb[16][17];
  const int t = threadIdx.x;

  // ---- stage U,V -> LDS as f16 d-pairs; thread t owns pair P=t ----
  {
    const float4* U4 = (const float4*)U;
    const float4* V4 = (const float4*)V;
    const int P = t;                  // d-pair (2P, 2P+1)
    const float4 a0 = U4[4 * P + 0], a1 = U4[4 * P + 1];  // U[2P][0..7]
    const float4 a2 = U4[4 * P + 2], a3 = U4[4 * P + 3];  // U[2P+1][0..7]
    const float4 b0 = V4[4 * P + 0], b1 = V4[4 * P + 1];
    const float4 b2 = V4[4 * P + 2], b3 = V4[4 * P + 3];
    uvQ[0][P] = make_uint4(pkh(a0.x, a2.x), pkh(a0.y, a2.y),
                           pkh(a0.z, a2.z), pkh(a0.w, a2.w));
    uvQ[1][P] = make_uint4(pkh(a1.x, a3.x), pkh(a1.y, a3.y),
                           pkh(a1.z, a3.z), pkh(a1.w, a3.w));
    uvQ[2][P] = make_uint4(pkh(b0.x, b2.x), pkh(b0.y, b2.y),
                           pkh(b0.z, b2.z), pkh(b0.w, b2.w));
    uvQ[3][P] = make_uint4(pkh(b1.x, b3.x), pkh(b1.y, b3.y),
                           pkh(b1.z, b3.z), pkh(b1.w, b3.w));
  }

  // ---- 16x16 setup (f32, from ws gram products) ----
  if (t < 192) prodS[t] = prod[t];
  __syncthreads();
  const float sg = 1.f / (1.f + expf(-gate[0]));
  if (t < 256) {
    const int r = t >> 4, c = t & 15;
    float g;
    if (r < 8) g = (c < 8) ? sg * prodS[64 + c * 8 + r]              // (V^T U)
                           : sg * prodS[128 + r * 8 + (c - 8)];      // (V^T V)
    else       g = (c < 8) ? -sg * prodS[(r - 8) * 8 + c]            // -(U^T U)
                           : -sg * prodS[64 + (r - 8) * 8 + (c - 8)];
    const float b = ((r == c) ? 1.f : 0.f) + 0.5f * g;
    Gs[r][c] = g;
    Bm[r][c] = b;
    Ya[r][c] = b;
  }
  __syncthreads();
#pragma unroll
  for (int m = 0; m < NEUMANN_ITERS; ++m) {   // ends in Ya (last m odd)
    if (t < 256) {
      const int r = t >> 4, c = t & 15;
      const float (*Yp)[17] = (m & 1) ? Yb : Ya;
      float (*Yn)[17] = (m & 1) ? Ya : Yb;
      float acc = Bm[r][c];
#pragma unroll
      for (int j = 0; j < 16; ++j)
        acc = fmaf(0.5f * Gs[r][j], Yp[j][c], acc);
      Yn[r][c] = acc;
    }
    __syncthreads();   // final barrier also orders uvQ staging before reads
  }

  // ---- main: 16 waves, 1 row/wave; lane owns d-pairs P = i*64+lane ----
  const int wv = t >> 6, lane = t & 63;
  const int row = blockIdx.x * 16 + wv;
  const float2* x2 = (const float2*)(x + (size_t)row * DIM);

  float a[16];
#pragma unroll
  for (int k = 0; k < 16; ++k) a[k] = 0.f;

  // phase 1: a = [x.U | x.V]
#pragma unroll 4
  for (int i = 0; i < 16; ++i) {
    const int P = i * 64 + lane;
    const float2 xp = x2[P];
    const uint4 qa = uvQ[0][P], qb = uvQ[1][P];
    const uint4 qc = uvQ[2][P], qd = uvQ[3][P];
#if __has_builtin(__builtin_amdgcn_fdot2)
    const h2 xh = cvt2h(xp.x, xp.y);
#define D2(acc, w) \
  acc = __builtin_amdgcn_fdot2(xh, __builtin_bit_cast(h2, w), acc, false)
    D2(a[0], qa.x);  D2(a[1], qa.y);  D2(a[2], qa.z);  D2(a[3], qa.w);
    D2(a[4], qb.x);  D2(a[5], qb.y);  D2(a[6], qb.z);  D2(a[7], qb.w);
    D2(a[8], qc.x);  D2(a[9], qc.y);  D2(a[10], qc.z); D2(a[11], qc.w);
    D2(a[12], qd.x); D2(a[13], qd.y); D2(a[14], qd.z); D2(a[15], qd.w);
#undef D2
#else
    const __half2 uu[16] = {
        __builtin_bit_cast(__half2, qa.x), __builtin_bit_cast(__half2, qa.y),
        __builtin_bit_cast(__half2, qa.z), __builtin_bit_cast(__half2, qa.w),
        __builtin_bit_cast(__half2, qb.x), __builtin_bit_cast(__half2, qb.y),
        __builtin_bit_cast(__half2, qb.z), __builtin_bit_cast(__half2, qb.w),
        __builtin_bit_cast(__half2, qc.x), __builtin_bit_cast(__half2, qc.y),
        __builtin_bit_cast(__half2, qc.z), __builtin_bit_cast(__half2, qc.w),
        __builtin_bit_cast(__half2, qd.x), __builtin_bit_cast(__half2, qd.y),
        __builtin_bit_cast(__half2, qd.z), __builtin_bit_cast(__half2, qd.w)};
#pragma unroll
    for (int k = 0; k < 16; ++k)
      a[k] = fmaf(xp.x, __low2float(uu[k]),
                  fmaf(xp.y, __high2float(uu[k]), a[k]));
#endif
  }

  // butterfly: 4 DPP VALU levels + 2 shuffles per value
#pragma unroll
  for (int k = 0; k < 16; ++k) a[k] = wave_red(a[k]);

  // c[k] = 0.5*s * sum_j Z[k][j] b[j]; lane kk=lane&15 computes row kk.
  __half2 ch[16];
  {
    const int kk = lane & 15;
    float zrow[16];
#pragma unroll
    for (int j = 0; j < 16; ++j)
      zrow[j] = Ya[kk][j] + ((j == kk) ? 1.f : 0.f);
    const float hs = 0.5f * sg;
    float s = 0.f;
#pragma unroll
    for (int j = 0; j < 8; ++j) {
      s = fmaf(zrow[j], a[8 + j], s);     //  Z[k][j]   * av[j]
      s = fmaf(-zrow[8 + j], a[j], s);    // -Z[k][8+j] * au[j]
    }
    const float cp = hs * s;
#pragma unroll
    for (int k = 0; k < 16; ++k) ch[k] = __float2half2_rn(__shfl(cp, k, 64));
  }

  // phase 2: out = x + sum_k c[k]*W[.][k]  (packed f16 fma, 2 chains)
  float2* o2 = (float2*)(out + (size_t)row * DIM);
  const __half2 hz = __float2half2_rn(0.f);
#define HF(acc, c, w) acc = __hfma2(c, __builtin_bit_cast(__half2, w), acc)
#pragma unroll 4
  for (int i = 0; i < 16; ++i) {
    const int P = i * 64 + lane;
    const uint4 qa = uvQ[0][P], qb = uvQ[1][P];
    const uint4 qc = uvQ[2][P], qd = uvQ[3][P];
    __half2 t0 = hz, t1 = hz;
    HF(t0, ch[0], qa.x);  HF(t0, ch[1], qa.y);
    HF(t0, ch[2], qa.z);  HF(t0, ch[3], qa.w);
    HF(t0, ch[4], qb.x);  HF(t0, ch[5], qb.y);
    HF(t0, ch[6], qb.z);  HF(t0, ch[7], qb.w);
    HF(t1, ch[8], qc.x);  HF(t1, ch[9], qc.y);
    HF(t1, ch[10], qc.z); HF(t1, ch[11], qc.w);
    HF(t1, ch[12], qd.x); HF(t1, ch[13], qd.y);
    HF(t1, ch[14], qd.z); HF(t1, ch[15], qd.w);
    const __half2 s = __hadd2(t0, t1);
    const float2 xp = x2[P];
    o2[P] = make_float2(xp.x + __low2float(s), xp.y + __high2float(s));
  }
#undef HF
}

extern "C" void kernel_launch(void* const* d_in, const int* in_sizes, int n_in,
                              void* d_out, int out_size, void* d_ws, size_t ws_size,
                              hipStream_t stream) {
  const float* x    = (const float*)d_in[0];
  const float* U    = (const float*)d_in[1];
  const float* V    = (const float*)d_in[2];
  const float* gate = (const float*)d_in[3];
  float* out = (float*)d_out;
  float* prodw = (float*)d_ws;   // 192 floats

  rora_gram<<<192, 256, 0, stream>>>(U, V, prodw);
  rora_fused<<<NTOK / 16, 1024, 0, stream>>>(x, U, V, gate, prodw, out);
}